// Round 9
// baseline (23515.485 us; speedup 1.0000x reference)
//
#include <hip/hip_runtime.h>
#include <cstdint>
#include <cstddef>

#define LSEQ 512
#define NBLK 256
#define ASZ (128*256*8)   // halfs per h parity plane (512 KB)

typedef _Float16 f16;
typedef f16 f16x8 __attribute__((ext_vector_type(8)));
typedef float f32x4 __attribute__((ext_vector_type(4)));
typedef unsigned long long u64t;
typedef unsigned int u32t;

#define MFMA16(a, b, c) __builtin_amdgcn_mfma_f32_16x16x32_f16(a, b, c, 0, 0, 0)

static __device__ __forceinline__ float sigm(float x){ return 1.f/(1.f+__expf(-x)); }
static __device__ __forceinline__ float tanh_f(float x){
    x = fminf(fmaxf(x,-15.f),15.f);
    float t = __expf(-2.f*x);
    return (1.f-t)/(1.f+t);
}
static __device__ __forceinline__ f16x8 cvt8(const float* s){
    float4 a = *(const float4*)s, b = *(const float4*)(s+4);
    f16x8 v = {(f16)a.x,(f16)a.y,(f16)a.z,(f16)a.w,(f16)b.x,(f16)b.y,(f16)b.z,(f16)b.w};
    return v;
}

// ---- R9 = R8 decomposition + two fixes:
// (1) __launch_bounds__(512,1): R8's (512,2) capped VGPR at 128 (observed)
//     -> the 192-VGPR weight set was rematerialized from L2 every step,
//     adding ~384 KB/block/step back onto the vmem pipe. With 8 waves =
//     2/SIMD the compiler must still cap at 256 -> weights stay resident.
// (2) 16B-contiguous h stores: R8's 2x4B scatter stores (16B stride) blew
//     WRITE_SIZE 1.05->3.17 GB (~4x line amplification). Epilogue is
//     re-partitioned: tid<128 own L0 (m x j-octet), tid 128..255 own L1;
//     each active thread computes 8 j and stores 2 contiguous u64.
// Model (fits R0-R8): step_time ~ per-CU vmem bytes / ~6.3 B/cyc.
typedef const __attribute__((address_space(1))) char gchar;
typedef __attribute__((address_space(3))) char lchar;
static __device__ __forceinline__ void dma16(const char* g, char* l){
    __builtin_amdgcn_global_load_lds((gchar*)g, (lchar*)l, 16, 0, 0x11);
}
// IC-coherent atomic ops (h stores + final read + barrier) — proven path.
static __device__ __forceinline__ u64t hload(const u64t* p){
    return __hip_atomic_load(p, __ATOMIC_RELAXED, __HIP_MEMORY_SCOPE_AGENT);
}
static __device__ __forceinline__ void hstore(u64t* p, u64t v){
    __hip_atomic_store(p, v, __ATOMIC_RELAXED, __HIP_MEMORY_SCOPE_AGENT);
}
union U2F16x8 { u64t q[2]; f16x8 v; };

// vmcnt waits (DMA pipeline, depth 3, 1 instr/chunk/wave): own-wave wait
// BEFORE s_barrier; the barrier publishes the other 7 waves' rows.
#define WAITVM2() __builtin_amdgcn_s_waitcnt(0x0F72)
#define WAITVM1() __builtin_amdgcn_s_waitcnt(0x0F71)
#define WAITVM0() __builtin_amdgcn_s_waitcnt(0x0F70)

// Single-level grid barrier (R0-proven form). vmcnt(0) drains h stores
// (acked at IC) before arrival.
static __device__ __forceinline__ void grid_barrier(int* bar){
    WAITVM0();
    __syncthreads();
    if (threadIdx.x == 0){
        int g = __hip_atomic_load(&bar[32], __ATOMIC_RELAXED, __HIP_MEMORY_SCOPE_AGENT);
        int old = __hip_atomic_fetch_add(&bar[0], 1, __ATOMIC_RELAXED, __HIP_MEMORY_SCOPE_AGENT);
        if (old == NBLK - 1){
            __hip_atomic_store(&bar[0], 0, __ATOMIC_RELAXED, __HIP_MEMORY_SCOPE_AGENT);
            __hip_atomic_store(&bar[32], g + 1, __ATOMIC_RELAXED, __HIP_MEMORY_SCOPE_AGENT);
        } else {
            while (__hip_atomic_load(&bar[32], __ATOMIC_RELAXED, __HIP_MEMORY_SCOPE_AGENT) == g)
                __builtin_amdgcn_s_sleep(2);
        }
    }
    __syncthreads();
}

// 256 blocks: nb = blk&63 (16 j-cols x 4 gates, shared col-tiling for BOTH
// layers), mh = blk>>6 (m0 = mh*64, 64 batch rows). 512 threads = 8 waves:
// nh = wav&3 = gate index (16 cols), kh = wav>>2 splits each K=1024 at 512.
// Per step p (uniform for all blocks):
//   phase A (chunks 0-15):  stage h0[p-1] -> acc0 += Whh0, acc1 += Wih1
//   phase B (chunks 16-31): stage h1[p-2] -> acc1 += Whh1
//   epilogue: kh-reduce via LDS; pointwise split L0/L1 across thread halves.
__global__ void __launch_bounds__(512, 1) lstm_persist(
    const float* __restrict__ seq,
    const float* __restrict__ Wih0, const float* __restrict__ Whh0,
    const float* __restrict__ bih0, const float* __restrict__ bhh0,
    const float* __restrict__ Wih1, const float* __restrict__ Whh1,
    const float* __restrict__ bih1, const float* __restrict__ bhh1,
    const float* __restrict__ linW, const float* __restrict__ linb,
    f16* __restrict__ A0, f16* __restrict__ A1, float* __restrict__ out,
    int* __restrict__ bar)
{
    __shared__ char  pool[35840] __attribute__((aligned(16))); // 4 DMA bufs x 8320 / epilogue 2x4352 f32
    __shared__ float ldsX[384];
    __shared__ float ldsWx[384];
    __shared__ float ldsB0[64];
    __shared__ float ldsB1[64];
    float* poolf = (float*)pool;

    const int tid = threadIdx.x, lane = tid & 63, wav = tid >> 6;
    const int quad = lane >> 4, l15 = lane & 15;
    const int nh = wav & 3, kh = wav >> 2;
    const int blk = blockIdx.x, nb = blk & 63, mh = blk >> 6;
    const int m0 = mh * 64, j0 = nb * 16;

    if (tid < 64){
        int R = (tid >> 4) * 1024 + j0 + (tid & 15);
        ldsB0[tid] = bih0[R] + bhh0[R];
        ldsB1[tid] = bih1[R] + bhh1[R];
    }
    if (tid < 384){
        int ct = tid / 6, i = tid - ct * 6;
        int R = (ct >> 4) * 1024 + j0 + (ct & 15);
        ldsWx[tid] = Wih0[(size_t)R * 6 + i];
    }
    // weights: per wave 16 cols (gate nh) x K-half (kh). 48 f16x8 = 192 VGPR.
    f16x8 w0[16], w1i[16], w1h[16];
    {
        const int Rw = nh * 1024 + j0 + l15;
        #pragma unroll
        for (int kg = 0; kg < 16; ++kg){
            size_t off = (size_t)Rw * 1024 + kh * 512 + kg * 32 + quad * 8;
            w0[kg]  = cvt8(Whh0 + off);
            w1i[kg] = cvt8(Wih1 + off);
            w1h[kg] = cvt8(Whh1 + off);
        }
    }
    // recurrent c-state: tid<128 holds L0 (8 j), tid in [128,256) holds L1.
    float cst[8];
    #pragma unroll
    for (int i = 0; i < 8; ++i) cst[i] = 0.f;

    for (int p = 0; p <= LSEQ; ++p){
        const char* P0 = (const char*)(A0 + (size_t)((p + 1) & 1) * ASZ); // h0[p-1]
        const char* P1 = (const char*)(A1 + (size_t)(p & 1) * ASZ);       // h1[p-2]
        u64t* W0p = (u64t*)(A0 + (size_t)(p & 1) * ASZ);                  // h0[p]
        u64t* W1p = (u64t*)(A1 + (size_t)((p + 1) & 1) * ASZ);            // h1[p-1]

        if (p < LSEQ && tid < 384) ldsX[tid] = seq[(size_t)p * 1536 + m0 * 6 + tid];

        f32x4 acc0[4], acc1[4];
        #pragma unroll
        for (int a = 0; a < 4; ++a){ acc0[a] = (f32x4){0,0,0,0}; acc1[a] = (f32x4){0,0,0,0}; }

        // prologue: DMA chunks 0..2 (all phase A -> P0)
        #pragma unroll
        for (int n = 0; n < 3; ++n)
            dma16(P0 + (size_t)(((n * 8 + wav) * 256 + m0 + lane) * 16),
                  pool + n * 8320 + wav * 1040 + lane * 16);

        #pragma unroll
        for (int c = 0; c < 32; ++c){
            if (c <= 29) WAITVM2(); else if (c == 30) WAITVM1(); else WAITVM0();
            __builtin_amdgcn_s_barrier();            // chunk c resident for all waves
            __builtin_amdgcn_sched_barrier(0);       // no ds_read hoisting above the wait
            if (c < 29){
                const int n = c + 3;
                const char* P = (n < 16) ? P0 : P1;
                const int kb = (n & 15) * 8;
                dma16(P + (size_t)(((kb + wav) * 256 + m0 + lane) * 16),
                      pool + (n & 3) * 8320 + wav * 1040 + lane * 16);
            }
            if (((c >> 3) & 1) == kh){
                const char* la = pool + (c & 3) * 8320;
                #pragma unroll
                for (int kgl = 0; kgl < 2; ++kgl){
                    const int ckg = (c & 7) * 2 + kgl;
                    #pragma unroll
                    for (int mt = 0; mt < 4; ++mt){
                        f16x8 af = *(const f16x8*)(la + (kgl * 4 + quad) * 1040 + (mt * 16 + l15) * 16);
                        if (c < 16){
                            acc0[mt] = MFMA16(af, w0[ckg],  acc0[mt]);
                            acc1[mt] = MFMA16(af, w1i[ckg], acc1[mt]);
                        } else {
                            acc1[mt] = MFMA16(af, w1h[ckg], acc1[mt]);
                        }
                    }
                }
            }
        }
        // ---- epilogue: kh-reduce both accs via LDS, pointwise, h stores ----
        __syncthreads();
        if (kh == 1){
            #pragma unroll
            for (int mt = 0; mt < 4; ++mt){
                int o = (nh * 16 + l15) * 68 + mt * 16 + quad * 4;
                *(f32x4*)(poolf + o)        = acc0[mt];
                *(f32x4*)(poolf + 4352 + o) = acc1[mt];
            }
        }
        __syncthreads();
        if (kh == 0){
            #pragma unroll
            for (int mt = 0; mt < 4; ++mt){
                int o = (nh * 16 + l15) * 68 + mt * 16 + quad * 4;
                f32x4 v0 = acc0[mt] + *(const f32x4*)(poolf + o);
                f32x4 v1 = acc1[mt] + *(const f32x4*)(poolf + 4352 + o);
                *(f32x4*)(poolf + o)        = v0;
                *(f32x4*)(poolf + 4352 + o) = v1;
            }
        }
        __syncthreads();
        // ---- pointwise: tid<128 -> L0 (m_l, oct); tid 128..255 -> L1 ----
        if (tid < 128 && p < LSEQ){
            const int m_l = tid & 63, oct = tid >> 6;   // 8 adjacent j per thread
            float xv[6];
            #pragma unroll
            for (int i = 0; i < 6; ++i) xv[i] = ldsX[m_l * 6 + i];
            f16 hh[8];
            #pragma unroll
            for (int s = 0; s < 8; ++s){
                int j = oct * 8 + s;
                float gv[4];
                #pragma unroll
                for (int g = 0; g < 4; ++g){
                    float v = poolf[(g * 16 + j) * 68 + m_l] + ldsB0[g * 16 + j];
                    #pragma unroll
                    for (int i = 0; i < 6; ++i) v += xv[i] * ldsWx[(g * 16 + j) * 6 + i];
                    gv[g] = v;
                }
                float I = sigm(gv[0]), F = sigm(gv[1]), G = tanh_f(gv[2]), O = sigm(gv[3]);
                float cn = F * cst[s] + I * G; cst[s] = cn;
                hh[s] = (f16)(O * tanh_f(cn));
            }
            const int kc8 = nb * 2 + oct;
            union { f16 h[8]; u64t q[2]; } pk;
            #pragma unroll
            for (int s = 0; s < 8; ++s) pk.h[s] = hh[s];
            u64t* dst = W0p + (size_t)(kc8 * 256 + m0 + m_l) * 2;
            hstore(dst,     pk.q[0]);
            hstore(dst + 1, pk.q[1]);
        } else if (tid >= 128 && tid < 256 && p >= 1){
            const int t2 = tid - 128;
            const int m_l = t2 & 63, oct = t2 >> 6;
            f16 hh[8];
            #pragma unroll
            for (int s = 0; s < 8; ++s){
                int j = oct * 8 + s;
                float gv[4];
                #pragma unroll
                for (int g = 0; g < 4; ++g)
                    gv[g] = poolf[4352 + (g * 16 + j) * 68 + m_l] + ldsB1[g * 16 + j];
                float I = sigm(gv[0]), F = sigm(gv[1]), G = tanh_f(gv[2]), O = sigm(gv[3]);
                float cn = F * cst[s] + I * G; cst[s] = cn;
                hh[s] = (f16)(O * tanh_f(cn));
            }
            const int kc8 = nb * 2 + oct;
            union { f16 h[8]; u64t q[2]; } pk;
            #pragma unroll
            for (int s = 0; s < 8; ++s) pk.h[s] = hh[s];
            u64t* dst = W1p + (size_t)(kc8 * 256 + m0 + m_l) * 2;
            hstore(dst,     pk.q[0]);
            hstore(dst + 1, pk.q[1]);
        }
        grid_barrier(bar);
    }
    // ---- final linear on h1[511] (plane parity (512+1)&1 = 1) ----
    if (blk < 64 && wav < 4){
        const u64t* hp = (const u64t*)(A1 + (size_t)ASZ);
        int n = blk * 4 + wav;
        float s = 0.f;
        #pragma unroll
        for (int u = 0; u < 2; ++u){
            int kc = u * 64 + lane;
            U2F16x8 t;
            t.q[0] = hload(hp + (size_t)(kc * 256 + n) * 2);
            t.q[1] = hload(hp + (size_t)(kc * 256 + n) * 2 + 1);
            #pragma unroll
            for (int j = 0; j < 8; ++j) s += (float)t.v[j] * linW[kc * 8 + j];
        }
        #pragma unroll
        for (int m = 32; m >= 1; m >>= 1) s += __shfl_xor(s, m, 64);
        if (lane == 0) out[n] = s + linb[0];
    }
}

extern "C" void kernel_launch(void* const* d_in, const int* in_sizes, int n_in,
                              void* d_out, int out_size, void* d_ws, size_t ws_size,
                              hipStream_t stream)
{
    (void)in_sizes; (void)n_in; (void)out_size; (void)ws_size;
    const float* seq  = (const float*)d_in[0];
    const float* Wih0 = (const float*)d_in[1];
    const float* Whh0 = (const float*)d_in[2];
    const float* bih0 = (const float*)d_in[3];
    const float* bhh0 = (const float*)d_in[4];
    const float* Wih1 = (const float*)d_in[5];
    const float* Whh1 = (const float*)d_in[6];
    const float* bih1 = (const float*)d_in[7];
    const float* bhh1 = (const float*)d_in[8];
    const float* linW = (const float*)d_in[9];
    const float* linb = (const float*)d_in[10];
    float* outp = (float*)d_out;

    char* ws = (char*)d_ws;
    f16* A0p = (f16*)ws;                      // h0: [2][128 kc8][256 m][8] = 1 MB
    f16* A1p = (f16*)(ws + (1 << 20));        // h1: 1 MB
    int* bar = (int*)(ws + (2 << 20));        // barrier state

    (void)hipMemsetAsync(ws, 0, 2 << 20, stream);   // zero h parity planes
    (void)hipMemsetAsync(bar, 0, 1024, stream);     // zero barrier state

    lstm_persist<<<dim3(NBLK), dim3(512), 0, stream>>>(
        seq, Wih0, Whh0, bih0, bhh0, Wih1, Whh1, bih1, bhh1, linW, linb,
        A0p, A1p, outp, bar);
}

// Round 10
// 20809.090 us; speedup vs baseline: 1.1301x; 1.1301x over previous
//
#include <hip/hip_runtime.h>
#include <cstdint>
#include <cstddef>

#define LSEQ 512
#define NBLK 256
#define ASZ (128*256*8)   // halfs per h parity plane (512 KB)

typedef _Float16 f16;
typedef f16 f16x8 __attribute__((ext_vector_type(8)));
typedef float f32x4 __attribute__((ext_vector_type(4)));
typedef unsigned long long u64t;

#define MFMA16(a, b, c) __builtin_amdgcn_mfma_f32_16x16x32_f16(a, b, c, 0, 0, 0)

static __device__ __forceinline__ float sigm(float x){ return 1.f/(1.f+__expf(-x)); }
static __device__ __forceinline__ float tanh_f(float x){
    x = fminf(fmaxf(x,-15.f),15.f);
    float t = __expf(-2.f*x);
    return (1.f-t)/(1.f+t);
}
static __device__ __forceinline__ f16x8 cvt8(const float* s){
    float4 a = *(const float4*)s, b = *(const float4*)(s+4);
    f16x8 v = {(f16)a.x,(f16)a.y,(f16)a.z,(f16)a.w,(f16)b.x,(f16)b.y,(f16)b.z,(f16)b.w};
    return v;
}

// ---- R10: merged-layer decomposition (R8's -19% win) restructured so the
// weights FIT in registers. R8/R9 evidence: 512-thread blocks pin the
// allocator at 128 VGPR/wave -> 192-VGPR weight set remats from L2 (R8) or
// spills to HBM scratch (R9, FETCH 18.5 GB). Per-wave weight bytes =
// block-volume / waves, so the fix is FEWER waves: 256 threads, 4 waves,
// 1 wave/SIMD -> up to 512 VGPR/wave (R0 precedent: compiler allocates
// 256+ in this regime). Each wave = one gate x 16 cols x FULL K=1024 x 3
// matrices = 96 f16x8 = 384 VGPR + 32 acc ~= 440 (m08: no spill <450).
// No kh-split -> epilogue K-reduce round eliminated.
typedef const __attribute__((address_space(1))) char gchar;
typedef __attribute__((address_space(3))) char lchar;
static __device__ __forceinline__ void dma16(const char* g, char* l){
    __builtin_amdgcn_global_load_lds((gchar*)g, (lchar*)l, 16, 0, 0x11);
}
// IC-coherent atomic ops (h stores + final read + barrier) — proven path.
static __device__ __forceinline__ u64t hload(const u64t* p){
    return __hip_atomic_load(p, __ATOMIC_RELAXED, __HIP_MEMORY_SCOPE_AGENT);
}
static __device__ __forceinline__ void hstore(u64t* p, u64t v){
    __hip_atomic_store(p, v, __ATOMIC_RELAXED, __HIP_MEMORY_SCOPE_AGENT);
}
union U2F16x8 { u64t q[2]; f16x8 v; };

// vmcnt waits: 2 DMA instr/chunk/wave, depth-3 prefetch -> wait to 4 (2
// newer chunks in flight), tail 2/0. Own-wave wait BEFORE s_barrier; the
// barrier publishes the other waves' rows (R5/R8-proven pattern).
#define WAITVM4() __builtin_amdgcn_s_waitcnt(0x0F74)
#define WAITVM2() __builtin_amdgcn_s_waitcnt(0x0F72)
#define WAITVM0() __builtin_amdgcn_s_waitcnt(0x0F70)

// Single-level grid barrier (R0-proven form).
static __device__ __forceinline__ void grid_barrier(int* bar){
    WAITVM0();
    __syncthreads();
    if (threadIdx.x == 0){
        int g = __hip_atomic_load(&bar[32], __ATOMIC_RELAXED, __HIP_MEMORY_SCOPE_AGENT);
        int old = __hip_atomic_fetch_add(&bar[0], 1, __ATOMIC_RELAXED, __HIP_MEMORY_SCOPE_AGENT);
        if (old == NBLK - 1){
            __hip_atomic_store(&bar[0], 0, __ATOMIC_RELAXED, __HIP_MEMORY_SCOPE_AGENT);
            __hip_atomic_store(&bar[32], g + 1, __ATOMIC_RELAXED, __HIP_MEMORY_SCOPE_AGENT);
        } else {
            while (__hip_atomic_load(&bar[32], __ATOMIC_RELAXED, __HIP_MEMORY_SCOPE_AGENT) == g)
                __builtin_amdgcn_s_sleep(2);
        }
    }
    __syncthreads();
}

// 256 blocks: nb = blk&63 (16 j-cols x 4 gates), mh = blk>>6 (m0 = mh*64).
// 256 threads = 4 waves; wave nh = gate index, full K per wave.
// Per step p (uniform for all blocks):
//   phase A (chunks 0-15):  stage h0[p-1] -> acc0 += Whh0, acc1 += Wih1
//   phase B (chunks 16-31): stage h1[p-2] -> acc1 += Whh1
//   epilogue: one acc->LDS round (no K-reduce); pointwise: tid<128 L0,
//   tid>=128 L1; 16B-contiguous h stores (R9-proven, WRITE_SIZE fix).
__global__ void __launch_bounds__(256, 1) lstm_persist(
    const float* __restrict__ seq,
    const float* __restrict__ Wih0, const float* __restrict__ Whh0,
    const float* __restrict__ bih0, const float* __restrict__ bhh0,
    const float* __restrict__ Wih1, const float* __restrict__ Whh1,
    const float* __restrict__ bih1, const float* __restrict__ bhh1,
    const float* __restrict__ linW, const float* __restrict__ linb,
    f16* __restrict__ A0, f16* __restrict__ A1, float* __restrict__ out,
    int* __restrict__ bar)
{
    __shared__ char  pool[34816] __attribute__((aligned(16))); // 4 DMA bufs x 8320 | epilogue 2 x 4352 f32
    __shared__ float ldsX[384];
    __shared__ float ldsWx[384];
    __shared__ float ldsB0[64];
    __shared__ float ldsB1[64];
    float* poolf = (float*)pool;

    const int tid = threadIdx.x, lane = tid & 63, wav = tid >> 6;
    const int quad = lane >> 4, l15 = lane & 15;
    const int nh = wav;                       // gate index, full K per wave
    const int blk = blockIdx.x, nb = blk & 63, mh = blk >> 6;
    const int m0 = mh * 64, j0 = nb * 16;

    if (tid < 64){
        int R = (tid >> 4) * 1024 + j0 + (tid & 15);
        ldsB0[tid] = bih0[R] + bhh0[R];
        ldsB1[tid] = bih1[R] + bhh1[R];
    }
    for (int t = tid; t < 384; t += 256){
        int ct = t / 6, i = t - ct * 6;
        int R = (ct >> 4) * 1024 + j0 + (ct & 15);
        ldsWx[t] = Wih0[(size_t)R * 6 + i];
    }
    // weights: per wave 16 cols (gate nh) x K=1024 x 3 mats = 96 f16x8.
    f16x8 w0[32], w1i[32], w1h[32];
    {
        const int Rw = nh * 1024 + j0 + l15;
        #pragma unroll
        for (int kg = 0; kg < 32; ++kg){
            size_t off = (size_t)Rw * 1024 + kg * 32 + quad * 8;
            w0[kg]  = cvt8(Whh0 + off);
            w1i[kg] = cvt8(Wih1 + off);
            w1h[kg] = cvt8(Whh1 + off);
        }
    }
    // recurrent c-state: tid<128 holds L0 (8 j), tid in [128,256) holds L1.
    float cst[8];
    #pragma unroll
    for (int i = 0; i < 8; ++i) cst[i] = 0.f;

    for (int p = 0; p <= LSEQ; ++p){
        const char* P0 = (const char*)(A0 + (size_t)((p + 1) & 1) * ASZ); // h0[p-1]
        const char* P1 = (const char*)(A1 + (size_t)(p & 1) * ASZ);       // h1[p-2]
        u64t* W0p = (u64t*)(A0 + (size_t)(p & 1) * ASZ);                  // h0[p]
        u64t* W1p = (u64t*)(A1 + (size_t)((p + 1) & 1) * ASZ);            // h1[p-1]

        if (p < LSEQ)
            for (int i = tid; i < 384; i += 256)
                ldsX[i] = seq[(size_t)p * 1536 + m0 * 6 + i];

        f32x4 acc0[4], acc1[4];
        #pragma unroll
        for (int a = 0; a < 4; ++a){ acc0[a] = (f32x4){0,0,0,0}; acc1[a] = (f32x4){0,0,0,0}; }

        // prologue: DMA chunks 0..2 (phase A -> P0); 2 instr/thread/chunk
        #pragma unroll
        for (int n = 0; n < 3; ++n)
            #pragma unroll
            for (int i = 0; i < 2; ++i)
                dma16(P0 + (size_t)(((n * 8 + i * 4 + wav) * 256 + m0 + lane) * 16),
                      pool + n * 8320 + (i * 4 + wav) * 1040 + lane * 16);

        #pragma unroll
        for (int c = 0; c < 32; ++c){
            if (c <= 29) WAITVM4(); else if (c == 30) WAITVM2(); else WAITVM0();
            __builtin_amdgcn_s_barrier();            // chunk c resident for all waves
            __builtin_amdgcn_sched_barrier(0);       // no ds_read hoisting above the wait
            if (c < 29){
                const int n = c + 3;
                const char* P = (n < 16) ? P0 : P1;
                const int kb = (n & 15) * 8;
                #pragma unroll
                for (int i = 0; i < 2; ++i)
                    dma16(P + (size_t)(((kb + i * 4 + wav) * 256 + m0 + lane) * 16),
                          pool + (n & 3) * 8320 + (i * 4 + wav) * 1040 + lane * 16);
            }
            {
                const char* la = pool + (c & 3) * 8320;
                #pragma unroll
                for (int kgl = 0; kgl < 2; ++kgl){
                    #pragma unroll
                    for (int mt = 0; mt < 4; ++mt){
                        f16x8 af = *(const f16x8*)(la + (kgl * 4 + quad) * 1040 + (mt * 16 + l15) * 16);
                        if (c < 16){
                            const int ckg = c * 2 + kgl;
                            acc0[mt] = MFMA16(af, w0[ckg],  acc0[mt]);
                            acc1[mt] = MFMA16(af, w1i[ckg], acc1[mt]);
                        } else {
                            const int ckg = (c - 16) * 2 + kgl;
                            acc1[mt] = MFMA16(af, w1h[ckg], acc1[mt]);
                        }
                    }
                }
            }
        }
        // ---- epilogue: single acc->LDS round (no K-reduce), pointwise ----
        __syncthreads();
        #pragma unroll
        for (int mt = 0; mt < 4; ++mt){
            int o = (nh * 16 + l15) * 68 + mt * 16 + quad * 4;
            *(f32x4*)(poolf + o)        = acc0[mt];
            *(f32x4*)(poolf + 4352 + o) = acc1[mt];
        }
        __syncthreads();
        // ---- pointwise: tid<128 -> L0 (m_l, oct); tid 128..255 -> L1 ----
        if (tid < 128 && p < LSEQ){
            const int m_l = tid & 63, oct = tid >> 6;   // 8 adjacent j per thread
            float xv[6];
            #pragma unroll
            for (int i = 0; i < 6; ++i) xv[i] = ldsX[m_l * 6 + i];
            f16 hh[8];
            #pragma unroll
            for (int s = 0; s < 8; ++s){
                int j = oct * 8 + s;
                float gv[4];
                #pragma unroll
                for (int g = 0; g < 4; ++g){
                    float v = poolf[(g * 16 + j) * 68 + m_l] + ldsB0[g * 16 + j];
                    #pragma unroll
                    for (int i = 0; i < 6; ++i) v += xv[i] * ldsWx[(g * 16 + j) * 6 + i];
                    gv[g] = v;
                }
                float I = sigm(gv[0]), F = sigm(gv[1]), G = tanh_f(gv[2]), O = sigm(gv[3]);
                float cn = F * cst[s] + I * G; cst[s] = cn;
                hh[s] = (f16)(O * tanh_f(cn));
            }
            const int kc8 = nb * 2 + oct;
            union { f16 h[8]; u64t q[2]; } pk;
            #pragma unroll
            for (int s = 0; s < 8; ++s) pk.h[s] = hh[s];
            u64t* dst = W0p + (size_t)(kc8 * 256 + m0 + m_l) * 2;
            hstore(dst,     pk.q[0]);
            hstore(dst + 1, pk.q[1]);
        } else if (tid >= 128 && p >= 1){
            const int t2 = tid - 128;
            const int m_l = t2 & 63, oct = t2 >> 6;
            f16 hh[8];
            #pragma unroll
            for (int s = 0; s < 8; ++s){
                int j = oct * 8 + s;
                float gv[4];
                #pragma unroll
                for (int g = 0; g < 4; ++g)
                    gv[g] = poolf[4352 + (g * 16 + j) * 68 + m_l] + ldsB1[g * 16 + j];
                float I = sigm(gv[0]), F = sigm(gv[1]), G = tanh_f(gv[2]), O = sigm(gv[3]);
                float cn = F * cst[s] + I * G; cst[s] = cn;
                hh[s] = (f16)(O * tanh_f(cn));
            }
            const int kc8 = nb * 2 + oct;
            union { f16 h[8]; u64t q[2]; } pk;
            #pragma unroll
            for (int s = 0; s < 8; ++s) pk.h[s] = hh[s];
            u64t* dst = W1p + (size_t)(kc8 * 256 + m0 + m_l) * 2;
            hstore(dst,     pk.q[0]);
            hstore(dst + 1, pk.q[1]);
        }
        grid_barrier(bar);
    }
    // ---- final linear on h1[511] (plane parity (512+1)&1 = 1) ----
    if (blk < 64){
        const u64t* hp = (const u64t*)(A1 + (size_t)ASZ);
        int n = blk * 4 + wav;
        float s = 0.f;
        #pragma unroll
        for (int u = 0; u < 2; ++u){
            int kc = u * 64 + lane;
            U2F16x8 t;
            t.q[0] = hload(hp + (size_t)(kc * 256 + n) * 2);
            t.q[1] = hload(hp + (size_t)(kc * 256 + n) * 2 + 1);
            #pragma unroll
            for (int j = 0; j < 8; ++j) s += (float)t.v[j] * linW[kc * 8 + j];
        }
        #pragma unroll
        for (int m = 32; m >= 1; m >>= 1) s += __shfl_xor(s, m, 64);
        if (lane == 0) out[n] = s + linb[0];
    }
}

extern "C" void kernel_launch(void* const* d_in, const int* in_sizes, int n_in,
                              void* d_out, int out_size, void* d_ws, size_t ws_size,
                              hipStream_t stream)
{
    (void)in_sizes; (void)n_in; (void)out_size; (void)ws_size;
    const float* seq  = (const float*)d_in[0];
    const float* Wih0 = (const float*)d_in[1];
    const float* Whh0 = (const float*)d_in[2];
    const float* bih0 = (const float*)d_in[3];
    const float* bhh0 = (const float*)d_in[4];
    const float* Wih1 = (const float*)d_in[5];
    const float* Whh1 = (const float*)d_in[6];
    const float* bih1 = (const float*)d_in[7];
    const float* bhh1 = (const float*)d_in[8];
    const float* linW = (const float*)d_in[9];
    const float* linb = (const float*)d_in[10];
    float* outp = (float*)d_out;

    char* ws = (char*)d_ws;
    f16* A0p = (f16*)ws;                      // h0: [2][128 kc8][256 m][8] = 1 MB
    f16* A1p = (f16*)(ws + (1 << 20));        // h1: 1 MB
    int* bar = (int*)(ws + (2 << 20));        // barrier state

    (void)hipMemsetAsync(ws, 0, 2 << 20, stream);   // zero h parity planes
    (void)hipMemsetAsync(bar, 0, 1024, stream);     // zero barrier state

    lstm_persist<<<dim3(NBLK), dim3(256), 0, stream>>>(
        seq, Wih0, Whh0, bih0, bhh0, Wih1, Whh1, bih1, bhh1, linW, linb,
        A0p, A1p, outp, bar);
}

// Round 11
// 14408.672 us; speedup vs baseline: 1.6320x; 1.4442x over previous
//
#include <hip/hip_runtime.h>
#include <cstdint>
#include <cstddef>

#define LSEQ 512
#define NBLK 256
#define ASZ (128*256*8)   // halfs per h plane (512 KB)
#define NPLN 8            // h rotation depth (write-once window)

typedef _Float16 f16;
typedef f16 f16x8 __attribute__((ext_vector_type(8)));
typedef float f32x4 __attribute__((ext_vector_type(4)));
typedef unsigned long long u64t;
typedef unsigned int u32t;

#define MFMA16(a, b, c) __builtin_amdgcn_mfma_f32_16x16x32_f16(a, b, c, 0, 0, 0)

static __device__ __forceinline__ float sigm(float x){ return 1.f/(1.f+__expf(-x)); }
static __device__ __forceinline__ float tanh_f(float x){
    x = fminf(fmaxf(x,-15.f),15.f);
    float t = __expf(-2.f*x);
    return (1.f-t)/(1.f+t);
}

// ---- R11: free-running waves. Ledger: lockstep LDS staging capped per-CU
// vmem at ~14-23 GB/s across R0-R10 (depth, cache mode, barrier count all
// null); register-resident weights impossible (4 waves->384 regs>256 cap,
// 8 waves->192>128 cap; spill = R9/R10 FETCH explosions). New structure:
// (1) A-frags loaded DIRECTLY global->VGPR, cached aux=0 -- all 4 waves
//     read identical addresses -> L1 broadcast; inter-block reuse -> L2.
// (2) Weights pre-converted to f16 ONCE (static-ctor hipMalloc buffer,
//     R6-proven legal) and streamed per-fragment from L2 (3 MB/XCD fits).
// (3) No LDS staging, no per-chunk barriers: per-wave depth-4 pipeline.
// (4) h coherence: R6-proven rotation (8 slots) + agent-acquire inv every
//     4 steps (slot read at r, rewritten r+7, re-read r+8: >=1 inv in any
//     7-step window). h writes stay agent-scope atomics (IC).
static __device__ __forceinline__ u64t hload(const u64t* p){
    return __hip_atomic_load(p, __ATOMIC_RELAXED, __HIP_MEMORY_SCOPE_AGENT);
}
static __device__ __forceinline__ void hstore(u64t* p, u64t v){
    __hip_atomic_store(p, v, __ATOMIC_RELAXED, __HIP_MEMORY_SCOPE_AGENT);
}
static __device__ __forceinline__ void hstore32(u32t* p, u32t v){
    __hip_atomic_store(p, v, __ATOMIC_RELAXED, __HIP_MEMORY_SCOPE_AGENT);
}
union U2F16x8 { u64t q[2]; f16x8 v; };

#define WAITVM0() __builtin_amdgcn_s_waitcnt(0x0F70)

// Single-level grid barrier (R0-proven). Optional agent-acquire on exit
// (one buffer_inv): L1/L2-cached h lines can't outlive a rotation cycle.
static __device__ __forceinline__ void grid_barrier(int* bar, bool inv){
    WAITVM0();                 // h stores acked at IC; pipeline drained
    __syncthreads();
    if (threadIdx.x == 0){
        int g = __hip_atomic_load(&bar[32], __ATOMIC_RELAXED, __HIP_MEMORY_SCOPE_AGENT);
        int old = __hip_atomic_fetch_add(&bar[0], 1, __ATOMIC_RELAXED, __HIP_MEMORY_SCOPE_AGENT);
        if (old == NBLK - 1){
            __hip_atomic_store(&bar[0], 0, __ATOMIC_RELAXED, __HIP_MEMORY_SCOPE_AGENT);
            __hip_atomic_store(&bar[32], g + 1, __ATOMIC_RELAXED, __HIP_MEMORY_SCOPE_AGENT);
        } else {
            while (__hip_atomic_load(&bar[32], __ATOMIC_RELAXED, __HIP_MEMORY_SCOPE_AGENT) == g)
                __builtin_amdgcn_s_sleep(2);
        }
    }
    __syncthreads();
    if (inv) __builtin_amdgcn_fence(__ATOMIC_ACQUIRE, "agent");
}

// 256 blocks: nb = blk&63 (16 j-cols x 4 gates), mh = blk>>6 (m0 = mh*64).
// 256 threads = 4 waves; wave nh = gate, full K. Per step: vc 0..31 phase A
// (A = h0[p-1]; B-mats Whh0 + Wih1), vc 32..63 phase B (A = h1[p-2]; Whh1).
// h slots: h0[t] in A0 slot (t+1)&7; h1[t] in A1 slot (t+1)&7.
__global__ void __launch_bounds__(256, 1) lstm_persist(
    const float* __restrict__ seq,
    const float* __restrict__ Wih0, const float* __restrict__ Whh0,
    const float* __restrict__ bih0, const float* __restrict__ bhh0,
    const float* __restrict__ Wih1, const float* __restrict__ Whh1,
    const float* __restrict__ bih1, const float* __restrict__ bhh1,
    const float* __restrict__ linW, const float* __restrict__ linb,
    f16* __restrict__ A0, f16* __restrict__ A1, f16* __restrict__ Wc,
    float* __restrict__ out, int* __restrict__ bar)
{
    __shared__ char  pool[34816] __attribute__((aligned(16)));  // epilogue 2 x 4352 f32
    __shared__ float ldsX[384];
    __shared__ float ldsWx[384];
    __shared__ float ldsB0[64];
    __shared__ float ldsB1[64];
    float* poolf = (float*)pool;

    const int tid = threadIdx.x, lane = tid & 63, wav = tid >> 6;
    const int quad = lane >> 4, l15 = lane & 15;
    const int nh = wav;
    const int blk = blockIdx.x, nb = blk & 63, mh = blk >> 6;
    const int m0 = mh * 64, j0 = nb * 16;

    if (tid < 64){
        int R = (tid >> 4) * 1024 + j0 + (tid & 15);
        ldsB0[tid] = bih0[R] + bhh0[R];
        ldsB1[tid] = bih1[R] + bhh1[R];
    }
    for (int t = tid; t < 384; t += 256){
        int ct = t / 6, i = t - ct * 6;
        int R = (ct >> 4) * 1024 + j0 + (ct & 15);
        ldsWx[t] = Wih0[(size_t)R * 6 + i];
    }

    // ---- one-time weight fp32->f16 conversion (mh==0 blocks only; row-major
    // [4096][1024] f16 per matrix: 0=Whh0, 1=Wih1, 2=Whh1). Agent stores ->
    // IC-visible; the pre-loop inv cleans all caches before cached reads.
    if (blk < 64){
        const float* S[3] = {Whh0, Wih1, Whh1};
        #pragma unroll
        for (int mat = 0; mat < 3; ++mat){
            u32t* D = (u32t*)Wc + (size_t)mat * (2u << 20);   // 8 MB / 4
            const float* Sm = S[mat];
            for (int idx = tid; idx < 64 * 512; idx += 256){
                int ri = idx >> 9, pr = idx & 511;
                int R = (ri >> 4) * 1024 + j0 + (ri & 15);
                float2 f = *(const float2*)(Sm + (size_t)R * 1024 + pr * 2);
                union { f16 h[2]; u32t w; } pk;
                pk.h[0] = (f16)f.x; pk.h[1] = (f16)f.y;
                hstore32(D + (size_t)R * 512 + pr, pk.w);
            }
        }
    }
    grid_barrier(bar, true);    // weights visible + all caches clean

    // per-wave invariant addressing
    const int Rw = nh * 1024 + j0 + l15;
    const char* pwBase = (const char*)Wc + ((size_t)Rw * 1024 + quad * 8) * 2;
    const char* pw0 = pwBase;                    // Whh0
    const char* pw1 = pwBase + (8u << 20);       // Wih1
    const char* pw2 = pwBase + (16u << 20);      // Whh1
    const int Aoff = quad * 4096 + (m0 + l15) * 16;

    // recurrent c-state: tid<128 holds L0 (8 j), tid in [128,256) holds L1.
    float cst[8];
    #pragma unroll
    for (int i = 0; i < 8; ++i) cst[i] = 0.f;

    for (int p = 0; p <= LSEQ; ++p){
        const char* P0 = (const char*)(A0 + (size_t)(p & 7) * ASZ);        // h0[p-1]
        const char* P1 = (const char*)(A1 + (size_t)((p + 7) & 7) * ASZ);  // h1[p-2]
        u64t* W0p = (u64t*)(A0 + (size_t)((p + 1) & 7) * ASZ);             // h0[p]
        u64t* W1p = (u64t*)(A1 + (size_t)(p & 7) * ASZ);                   // h1[p-1]

        if (p < LSEQ)
            for (int i = tid; i < 384; i += 256)
                ldsX[i] = seq[(size_t)p * 1536 + m0 * 6 + i];

        f32x4 acc0[4], acc1[4];
        #pragma unroll
        for (int a = 0; a < 4; ++a){ acc0[a] = (f32x4){0,0,0,0}; acc1[a] = (f32x4){0,0,0,0}; }

        uint4 ab[4][4], wb[4][2];

#define LOADS(vc_, sl_) do{ \
        const char* Pa_ = ((vc_) < 32) ? P0 : P1; \
        const int cc_ = (vc_) & 31; \
        ab[sl_][0] = *(const uint4*)(Pa_ + (Aoff + cc_ * 16384 +   0)); \
        ab[sl_][1] = *(const uint4*)(Pa_ + (Aoff + cc_ * 16384 + 256)); \
        ab[sl_][2] = *(const uint4*)(Pa_ + (Aoff + cc_ * 16384 + 512)); \
        ab[sl_][3] = *(const uint4*)(Pa_ + (Aoff + cc_ * 16384 + 768)); \
        if ((vc_) < 32){ \
            wb[sl_][0] = *(const uint4*)(pw0 + cc_ * 64); \
            wb[sl_][1] = *(const uint4*)(pw1 + cc_ * 64); \
        } else { \
            wb[sl_][0] = *(const uint4*)(pw2 + cc_ * 64); \
        } }while(0)

        LOADS(0, 0); LOADS(1, 1); LOADS(2, 2);
        #pragma unroll
        for (int vc = 0; vc < 64; ++vc){
            if (vc < 61) LOADS(vc + 3, (vc + 3) & 3);   // issue ahead (depth 4)
            {
                const int sl = vc & 3;
                if (vc < 32){
                    f16x8 b0 = __builtin_bit_cast(f16x8, wb[sl][0]);
                    f16x8 b1 = __builtin_bit_cast(f16x8, wb[sl][1]);
                    #pragma unroll
                    for (int mt = 0; mt < 4; ++mt){
                        f16x8 a = __builtin_bit_cast(f16x8, ab[sl][mt]);
                        acc0[mt] = MFMA16(a, b0, acc0[mt]);
                        acc1[mt] = MFMA16(a, b1, acc1[mt]);
                    }
                } else {
                    f16x8 b = __builtin_bit_cast(f16x8, wb[sl][0]);
                    #pragma unroll
                    for (int mt = 0; mt < 4; ++mt)
                        acc1[mt] = MFMA16(__builtin_bit_cast(f16x8, ab[sl][mt]), b, acc1[mt]);
                }
            }
            __builtin_amdgcn_sched_barrier(0);   // pin depth-4 order (no hoist pile-up)
        }
#undef LOADS

        // ---- epilogue (R10-proven): acc->LDS, pointwise, 16B h stores ----
        __syncthreads();
        #pragma unroll
        for (int mt = 0; mt < 4; ++mt){
            int o = (nh * 16 + l15) * 68 + mt * 16 + quad * 4;
            *(f32x4*)(poolf + o)        = acc0[mt];
            *(f32x4*)(poolf + 4352 + o) = acc1[mt];
        }
        __syncthreads();
        if (tid < 128 && p < LSEQ){
            const int m_l = tid & 63, oct = tid >> 6;   // 8 adjacent j per thread
            float xv[6];
            #pragma unroll
            for (int i = 0; i < 6; ++i) xv[i] = ldsX[m_l * 6 + i];
            f16 hh[8];
            #pragma unroll
            for (int s = 0; s < 8; ++s){
                int j = oct * 8 + s;
                float gv[4];
                #pragma unroll
                for (int g = 0; g < 4; ++g){
                    float v = poolf[(g * 16 + j) * 68 + m_l] + ldsB0[g * 16 + j];
                    #pragma unroll
                    for (int i = 0; i < 6; ++i) v += xv[i] * ldsWx[(g * 16 + j) * 6 + i];
                    gv[g] = v;
                }
                float I = sigm(gv[0]), F = sigm(gv[1]), G = tanh_f(gv[2]), O = sigm(gv[3]);
                float cn = F * cst[s] + I * G; cst[s] = cn;
                hh[s] = (f16)(O * tanh_f(cn));
            }
            const int kc8 = nb * 2 + oct;
            union { f16 h[8]; u64t q[2]; } pk;
            #pragma unroll
            for (int s = 0; s < 8; ++s) pk.h[s] = hh[s];
            u64t* dst = W0p + (size_t)(kc8 * 256 + m0 + m_l) * 2;
            hstore(dst,     pk.q[0]);
            hstore(dst + 1, pk.q[1]);
        } else if (tid >= 128 && p >= 1){
            const int t2 = tid - 128;
            const int m_l = t2 & 63, oct = t2 >> 6;
            f16 hh[8];
            #pragma unroll
            for (int s = 0; s < 8; ++s){
                int j = oct * 8 + s;
                float gv[4];
                #pragma unroll
                for (int g = 0; g < 4; ++g)
                    gv[g] = poolf[4352 + (g * 16 + j) * 68 + m_l] + ldsB1[g * 16 + j];
                float I = sigm(gv[0]), F = sigm(gv[1]), G = tanh_f(gv[2]), O = sigm(gv[3]);
                float cn = F * cst[s] + I * G; cst[s] = cn;
                hh[s] = (f16)(O * tanh_f(cn));
            }
            const int kc8 = nb * 2 + oct;
            union { f16 h[8]; u64t q[2]; } pk;
            #pragma unroll
            for (int s = 0; s < 8; ++s) pk.h[s] = hh[s];
            u64t* dst = W1p + (size_t)(kc8 * 256 + m0 + m_l) * 2;
            hstore(dst,     pk.q[0]);
            hstore(dst + 1, pk.q[1]);
        }
        grid_barrier(bar, (p & 3) == 3);
    }
    // ---- final linear on h1[511] (slot (511+1)&7 = 0) ----
    if (blk < 64){
        const u64t* hp = (const u64t*)A1;
        int n = blk * 4 + wav;
        float s = 0.f;
        #pragma unroll
        for (int u = 0; u < 2; ++u){
            int kc = u * 64 + lane;
            U2F16x8 t;
            t.q[0] = hload(hp + (size_t)(kc * 256 + n) * 2);
            t.q[1] = hload(hp + (size_t)(kc * 256 + n) * 2 + 1);
            #pragma unroll
            for (int j = 0; j < 8; ++j) s += (float)t.v[j] * linW[kc * 8 + j];
        }
        #pragma unroll
        for (int m = 32; m >= 1; m >>= 1) s += __shfl_xor(s, m, 64);
        if (lane == 0) out[n] = s + linb[0];
    }
}

// One-time cacheable device allocation at .so load for the f16 weight copy
// (outside graph capture -- R6-proven legal). Fallback: ws + 17 MB.
static void* g_wbuf = nullptr;
static struct WBufInit {
    WBufInit(){
        void* p = nullptr;
        if (hipMalloc(&p, (size_t)24 << 20) == hipSuccess) g_wbuf = p;
    }
} g_wbuf_init;

extern "C" void kernel_launch(void* const* d_in, const int* in_sizes, int n_in,
                              void* d_out, int out_size, void* d_ws, size_t ws_size,
                              hipStream_t stream)
{
    (void)in_sizes; (void)n_in; (void)out_size; (void)ws_size;
    const float* seq  = (const float*)d_in[0];
    const float* Wih0 = (const float*)d_in[1];
    const float* Whh0 = (const float*)d_in[2];
    const float* bih0 = (const float*)d_in[3];
    const float* bhh0 = (const float*)d_in[4];
    const float* Wih1 = (const float*)d_in[5];
    const float* Whh1 = (const float*)d_in[6];
    const float* bih1 = (const float*)d_in[7];
    const float* bhh1 = (const float*)d_in[8];
    const float* linW = (const float*)d_in[9];
    const float* linb = (const float*)d_in[10];
    float* outp = (float*)d_out;

    char* ws = (char*)d_ws;
    f16* A0p = (f16*)ws;                      // h0: 8 planes x 512 KB = 4 MB
    f16* A1p = (f16*)(ws + (4 << 20));        // h1: 8 planes x 512 KB = 4 MB
    int* bar = (int*)(ws + (16 << 20));       // barrier state (proven offset)
    f16* Wcp = g_wbuf ? (f16*)g_wbuf : (f16*)(ws + (17 << 20));  // f16 weights, 24 MB

    // zero only the t=-1 slots (slot 0 of each plane array) + barrier
    (void)hipMemsetAsync(ws, 0, 1 << 19, stream);              // A0 slot 0
    (void)hipMemsetAsync(ws + (4 << 20), 0, 1 << 19, stream);  // A1 slot 0
    (void)hipMemsetAsync(bar, 0, 1024, stream);                // barrier

    lstm_persist<<<dim3(NBLK), dim3(256), 0, stream>>>(
        seq, Wih0, Whh0, bih0, bhh0, Wih1, Whh1, bih1, bhh1, linW, linb,
        A0p, A1p, Wcp, outp, bar);
}

// Round 12
// 13054.973 us; speedup vs baseline: 1.8013x; 1.1037x over previous
//
#include <hip/hip_runtime.h>
#include <cstdint>
#include <cstddef>

#define LSEQ 512
#define NBLK 256
#define ASZ (128*256*8)   // halfs per h plane (512 KB)
#define NPLN 16           // h rotation depth (write-once window)

typedef _Float16 f16;
typedef f16 f16x8 __attribute__((ext_vector_type(8)));
typedef float f32x4 __attribute__((ext_vector_type(4)));
typedef unsigned long long u64t;
typedef unsigned int u32t;

#define MFMA16(a, b, c) __builtin_amdgcn_mfma_f32_16x16x32_f16(a, b, c, 0, 0, 0)

static __device__ __forceinline__ float sigm(float x){ return 1.f/(1.f+__expf(-x)); }
static __device__ __forceinline__ float tanh_f(float x){
    x = fminf(fmaxf(x,-15.f),15.f);
    float t = __expf(-2.f*x);
    return (1.f-t)/(1.f+t);
}

// ---- R12 = R11 free-running structure + XCD-aware weight residency.
// R11 post-mortem: blocks on one XCD carried 32 distinct nb -> 12 MB weight
// working set vs 4 MB L2 -> permanent thrash re-served over the IC fabric
// every step (~the unexplained 2x). Remap (bijective):
//   x=blk&7 (XCD under blk%8 round-robin), k=blk>>3,
//   nb = x*8 + (k>>2)  -> 8 distinct nb per XCD -> 3 MB weights, L2-FITS
//   mh = k&3           -> all 4 m-slices per XCD (h = 1 MB/step, unchanged)
// Plus: rotation depth 16 with inv every 8 steps (halves inv-forced weight
// refetch; slot filled at W+1, rewritten W+16, re-read W+17 -> >=1 inv in
// window); two-level barrier with 8 per-group release lines (32 pollers per
// line, not 256). A-frags: direct global->VGPR cached loads (L1 broadcasts
// across the 4 waves); weights: f16 pre-converted once (static-ctor
// hipMalloc, R6-proven) and streamed from the now-resident L2.
static __device__ __forceinline__ u64t hload(const u64t* p){
    return __hip_atomic_load(p, __ATOMIC_RELAXED, __HIP_MEMORY_SCOPE_AGENT);
}
static __device__ __forceinline__ void hstore(u64t* p, u64t v){
    __hip_atomic_store(p, v, __ATOMIC_RELAXED, __HIP_MEMORY_SCOPE_AGENT);
}
static __device__ __forceinline__ void hstore32(u32t* p, u32t v){
    __hip_atomic_store(p, v, __ATOMIC_RELAXED, __HIP_MEMORY_SCOPE_AGENT);
}
union U2F16x8 { u64t q[2]; f16x8 v; };

#define WAITVM0() __builtin_amdgcn_s_waitcnt(0x0F70)

// Two-level grid barrier: per-group arrival counters (bar[grp*16], 32
// arrivals each), root (bar[128]), 8 release words (bar[160+grp*16]) all
// written by the final releaser -> poll contention 256->32 per line.
// Optional agent-acquire on exit (one buffer_inv per 8 steps).
static __device__ __forceinline__ void grid_barrier(int* bar, int grp, bool inv){
    WAITVM0();                 // h stores acked at IC; pipeline drained
    __syncthreads();
    if (threadIdx.x == 0){
        int g = __hip_atomic_load(&bar[160 + grp * 16], __ATOMIC_RELAXED, __HIP_MEMORY_SCOPE_AGENT);
        int old = __hip_atomic_fetch_add(&bar[grp * 16], 1, __ATOMIC_RELAXED, __HIP_MEMORY_SCOPE_AGENT);
        if (old == (NBLK / 8) - 1){
            __hip_atomic_store(&bar[grp * 16], 0, __ATOMIC_RELAXED, __HIP_MEMORY_SCOPE_AGENT);
            int r = __hip_atomic_fetch_add(&bar[128], 1, __ATOMIC_RELAXED, __HIP_MEMORY_SCOPE_AGENT);
            if (r == 7){
                __hip_atomic_store(&bar[128], 0, __ATOMIC_RELAXED, __HIP_MEMORY_SCOPE_AGENT);
                #pragma unroll
                for (int i = 0; i < 8; ++i)
                    __hip_atomic_store(&bar[160 + i * 16], g + 1, __ATOMIC_RELAXED, __HIP_MEMORY_SCOPE_AGENT);
            } else {
                while (__hip_atomic_load(&bar[160 + grp * 16], __ATOMIC_RELAXED, __HIP_MEMORY_SCOPE_AGENT) == g)
                    __builtin_amdgcn_s_sleep(1);
            }
        } else {
            while (__hip_atomic_load(&bar[160 + grp * 16], __ATOMIC_RELAXED, __HIP_MEMORY_SCOPE_AGENT) == g)
                __builtin_amdgcn_s_sleep(2);
        }
    }
    __syncthreads();
    if (inv) __builtin_amdgcn_fence(__ATOMIC_ACQUIRE, "agent");
}

// 256 threads = 4 waves; wave nh = gate, full K. Per step: vc 0..31 phase A
// (A = h0[p-1]; B-mats Whh0 + Wih1), vc 32..63 phase B (A = h1[p-2]; Whh1).
// h slots: h0[t] in A0 slot (t+1)&15; h1[t] in A1 slot (t+1)&15.
__global__ void __launch_bounds__(256, 1) lstm_persist(
    const float* __restrict__ seq,
    const float* __restrict__ Wih0, const float* __restrict__ Whh0,
    const float* __restrict__ bih0, const float* __restrict__ bhh0,
    const float* __restrict__ Wih1, const float* __restrict__ Whh1,
    const float* __restrict__ bih1, const float* __restrict__ bhh1,
    const float* __restrict__ linW, const float* __restrict__ linb,
    f16* __restrict__ A0, f16* __restrict__ A1, f16* __restrict__ Wc,
    float* __restrict__ out, int* __restrict__ bar)
{
    __shared__ char  pool[34816] __attribute__((aligned(16)));  // epilogue 2 x 4352 f32
    __shared__ float ldsX[384];
    __shared__ float ldsWx[384];
    __shared__ float ldsB0[64];
    __shared__ float ldsB1[64];
    float* poolf = (float*)pool;

    const int tid = threadIdx.x, lane = tid & 63, wav = tid >> 6;
    const int quad = lane >> 4, l15 = lane & 15;
    const int nh = wav;
    const int blk = blockIdx.x;
    const int xcd = blk & 7, kk = blk >> 3;
    const int nb = xcd * 8 + (kk >> 2), mh = kk & 3;   // XCD-resident weights
    const int m0 = mh * 64, j0 = nb * 16;

    if (tid < 64){
        int R = (tid >> 4) * 1024 + j0 + (tid & 15);
        ldsB0[tid] = bih0[R] + bhh0[R];
        ldsB1[tid] = bih1[R] + bhh1[R];
    }
    for (int t = tid; t < 384; t += 256){
        int ct = t / 6, i = t - ct * 6;
        int R = (ct >> 4) * 1024 + j0 + (ct & 15);
        ldsWx[t] = Wih0[(size_t)R * 6 + i];
    }

    // ---- one-time weight fp32->f16 conversion, mapping-independent:
    // block blk converts rows [blk*16, blk*16+16) of each matrix
    // (row-major [4096][1024] f16; 0=Whh0, 1=Wih1, 2=Whh1).
    {
        const float* S[3] = {Whh0, Wih1, Whh1};
        #pragma unroll
        for (int mat = 0; mat < 3; ++mat){
            u32t* D = (u32t*)Wc + (size_t)mat * (2u << 20);   // 8 MB / 4
            const float* Sm = S[mat];
            for (int idx = tid; idx < 16 * 512; idx += 256){
                int r = idx >> 9, pr = idx & 511;
                int R = blk * 16 + r;
                float2 f = *(const float2*)(Sm + (size_t)R * 1024 + pr * 2);
                union { f16 h[2]; u32t w; } pk;
                pk.h[0] = (f16)f.x; pk.h[1] = (f16)f.y;
                hstore32(D + (size_t)R * 512 + pr, pk.w);
            }
        }
    }
    grid_barrier(bar, xcd, true);    // weights visible + all caches clean

    // per-wave invariant addressing
    const int Rw = nh * 1024 + j0 + l15;
    const char* pwBase = (const char*)Wc + ((size_t)Rw * 1024 + quad * 8) * 2;
    const char* pw0 = pwBase;                    // Whh0
    const char* pw1 = pwBase + (8u << 20);       // Wih1
    const char* pw2 = pwBase + (16u << 20);      // Whh1
    const int Aoff = quad * 4096 + (m0 + l15) * 16;

    // recurrent c-state: tid<128 holds L0 (8 j), tid in [128,256) holds L1.
    float cst[8];
    #pragma unroll
    for (int i = 0; i < 8; ++i) cst[i] = 0.f;

    for (int p = 0; p <= LSEQ; ++p){
        const char* P0 = (const char*)(A0 + (size_t)(p & 15) * ASZ);        // h0[p-1]
        const char* P1 = (const char*)(A1 + (size_t)((p + 15) & 15) * ASZ); // h1[p-2] (p=0: garbage, discarded)
        u64t* W0p = (u64t*)(A0 + (size_t)((p + 1) & 15) * ASZ);             // h0[p]
        u64t* W1p = (u64t*)(A1 + (size_t)(p & 15) * ASZ);                   // h1[p-1]

        if (p < LSEQ)
            for (int i = tid; i < 384; i += 256)
                ldsX[i] = seq[(size_t)p * 1536 + m0 * 6 + i];

        f32x4 acc0[4], acc1[4];
        #pragma unroll
        for (int a = 0; a < 4; ++a){ acc0[a] = (f32x4){0,0,0,0}; acc1[a] = (f32x4){0,0,0,0}; }

        uint4 ab[4][4], wb[4][2];

#define LOADS(vc_, sl_) do{ \
        const char* Pa_ = ((vc_) < 32) ? P0 : P1; \
        const int cc_ = (vc_) & 31; \
        ab[sl_][0] = *(const uint4*)(Pa_ + (Aoff + cc_ * 16384 +   0)); \
        ab[sl_][1] = *(const uint4*)(Pa_ + (Aoff + cc_ * 16384 + 256)); \
        ab[sl_][2] = *(const uint4*)(Pa_ + (Aoff + cc_ * 16384 + 512)); \
        ab[sl_][3] = *(const uint4*)(Pa_ + (Aoff + cc_ * 16384 + 768)); \
        if ((vc_) < 32){ \
            wb[sl_][0] = *(const uint4*)(pw0 + cc_ * 64); \
            wb[sl_][1] = *(const uint4*)(pw1 + cc_ * 64); \
        } else { \
            wb[sl_][0] = *(const uint4*)(pw2 + cc_ * 64); \
        } }while(0)

        LOADS(0, 0); LOADS(1, 1); LOADS(2, 2);
        #pragma unroll
        for (int vc = 0; vc < 64; ++vc){
            if (vc < 61) LOADS(vc + 3, (vc + 3) & 3);   // issue ahead (depth 4)
            {
                const int sl = vc & 3;
                if (vc < 32){
                    f16x8 b0 = __builtin_bit_cast(f16x8, wb[sl][0]);
                    f16x8 b1 = __builtin_bit_cast(f16x8, wb[sl][1]);
                    #pragma unroll
                    for (int mt = 0; mt < 4; ++mt){
                        f16x8 a = __builtin_bit_cast(f16x8, ab[sl][mt]);
                        acc0[mt] = MFMA16(a, b0, acc0[mt]);
                        acc1[mt] = MFMA16(a, b1, acc1[mt]);
                    }
                } else {
                    f16x8 b = __builtin_bit_cast(f16x8, wb[sl][0]);
                    #pragma unroll
                    for (int mt = 0; mt < 4; ++mt)
                        acc1[mt] = MFMA16(__builtin_bit_cast(f16x8, ab[sl][mt]), b, acc1[mt]);
                }
            }
            __builtin_amdgcn_sched_barrier(0);   // pin depth-4 order (no hoist pile-up)
        }
#undef LOADS

        // ---- epilogue (R10/R11-proven): acc->LDS, pointwise, 16B h stores ----
        __syncthreads();
        #pragma unroll
        for (int mt = 0; mt < 4; ++mt){
            int o = (nh * 16 + l15) * 68 + mt * 16 + quad * 4;
            *(f32x4*)(poolf + o)        = acc0[mt];
            *(f32x4*)(poolf + 4352 + o) = acc1[mt];
        }
        __syncthreads();
        if (tid < 128 && p < LSEQ){
            const int m_l = tid & 63, oct = tid >> 6;   // 8 adjacent j per thread
            float xv[6];
            #pragma unroll
            for (int i = 0; i < 6; ++i) xv[i] = ldsX[m_l * 6 + i];
            f16 hh[8];
            #pragma unroll
            for (int s = 0; s < 8; ++s){
                int j = oct * 8 + s;
                float gv[4];
                #pragma unroll
                for (int g = 0; g < 4; ++g){
                    float v = poolf[(g * 16 + j) * 68 + m_l] + ldsB0[g * 16 + j];
                    #pragma unroll
                    for (int i = 0; i < 6; ++i) v += xv[i] * ldsWx[(g * 16 + j) * 6 + i];
                    gv[g] = v;
                }
                float I = sigm(gv[0]), F = sigm(gv[1]), G = tanh_f(gv[2]), O = sigm(gv[3]);
                float cn = F * cst[s] + I * G; cst[s] = cn;
                hh[s] = (f16)(O * tanh_f(cn));
            }
            const int kc8 = nb * 2 + oct;
            union { f16 h[8]; u64t q[2]; } pk;
            #pragma unroll
            for (int s = 0; s < 8; ++s) pk.h[s] = hh[s];
            u64t* dst = W0p + (size_t)(kc8 * 256 + m0 + m_l) * 2;
            hstore(dst,     pk.q[0]);
            hstore(dst + 1, pk.q[1]);
        } else if (tid >= 128 && p >= 1){
            const int t2 = tid - 128;
            const int m_l = t2 & 63, oct = t2 >> 6;
            f16 hh[8];
            #pragma unroll
            for (int s = 0; s < 8; ++s){
                int j = oct * 8 + s;
                float gv[4];
                #pragma unroll
                for (int g = 0; g < 4; ++g)
                    gv[g] = poolf[4352 + (g * 16 + j) * 68 + m_l] + ldsB1[g * 16 + j];
                float I = sigm(gv[0]), F = sigm(gv[1]), G = tanh_f(gv[2]), O = sigm(gv[3]);
                float cn = F * cst[s] + I * G; cst[s] = cn;
                hh[s] = (f16)(O * tanh_f(cn));
            }
            const int kc8 = nb * 2 + oct;
            union { f16 h[8]; u64t q[2]; } pk;
            #pragma unroll
            for (int s = 0; s < 8; ++s) pk.h[s] = hh[s];
            u64t* dst = W1p + (size_t)(kc8 * 256 + m0 + m_l) * 2;
            hstore(dst,     pk.q[0]);
            hstore(dst + 1, pk.q[1]);
        }
        grid_barrier(bar, xcd, (p & 7) == 7);
    }
    // ---- final linear on h1[511] (slot (511+1)&15 = 0) ----
    if (blk < 64){
        const u64t* hp = (const u64t*)A1;
        int n = blk * 4 + wav;
        float s = 0.f;
        #pragma unroll
        for (int u = 0; u < 2; ++u){
            int kc = u * 64 + lane;
            U2F16x8 t;
            t.q[0] = hload(hp + (size_t)(kc * 256 + n) * 2);
            t.q[1] = hload(hp + (size_t)(kc * 256 + n) * 2 + 1);
            #pragma unroll
            for (int j = 0; j < 8; ++j) s += (float)t.v[j] * linW[kc * 8 + j];
        }
        #pragma unroll
        for (int m = 32; m >= 1; m >>= 1) s += __shfl_xor(s, m, 64);
        if (lane == 0) out[n] = s + linb[0];
    }
}

// One-time cacheable device allocation at .so load for the f16 weight copy
// (outside graph capture -- R6/R11-proven legal). Fallback: ws + 17 MB.
static void* g_wbuf = nullptr;
static struct WBufInit {
    WBufInit(){
        void* p = nullptr;
        if (hipMalloc(&p, (size_t)24 << 20) == hipSuccess) g_wbuf = p;
    }
} g_wbuf_init;

extern "C" void kernel_launch(void* const* d_in, const int* in_sizes, int n_in,
                              void* d_out, int out_size, void* d_ws, size_t ws_size,
                              hipStream_t stream)
{
    (void)in_sizes; (void)n_in; (void)out_size; (void)ws_size;
    const float* seq  = (const float*)d_in[0];
    const float* Wih0 = (const float*)d_in[1];
    const float* Whh0 = (const float*)d_in[2];
    const float* bih0 = (const float*)d_in[3];
    const float* bhh0 = (const float*)d_in[4];
    const float* Wih1 = (const float*)d_in[5];
    const float* Whh1 = (const float*)d_in[6];
    const float* bih1 = (const float*)d_in[7];
    const float* bhh1 = (const float*)d_in[8];
    const float* linW = (const float*)d_in[9];
    const float* linb = (const float*)d_in[10];
    float* outp = (float*)d_out;

    char* ws = (char*)d_ws;
    f16* A0p = (f16*)ws;                      // h0: 16 planes x 512 KB = 8 MB
    f16* A1p = (f16*)(ws + (8 << 20));        // h1: 16 planes x 512 KB = 8 MB
    int* bar = (int*)(ws + (16 << 20));       // barrier state
    f16* Wcp = g_wbuf ? (f16*)g_wbuf : (f16*)(ws + (17 << 20));  // f16 weights, 24 MB

    // zero only the t=-1 slots (slot 0 of each plane array) + barrier
    (void)hipMemsetAsync(ws, 0, 1 << 19, stream);              // A0 slot 0
    (void)hipMemsetAsync(ws + (8 << 20), 0, 1 << 19, stream);  // A1 slot 0
    (void)hipMemsetAsync(bar, 0, 2048, stream);                // barrier state

    lstm_persist<<<dim3(NBLK), dim3(256), 0, stream>>>(
        seq, Wih0, Whh0, bih0, bhh0, Wih1, Whh1, bih1, bhh1, linW, linb,
        A0p, A1p, Wcp, outp, bar);
}